// Round 1
// baseline (270.240 us; speedup 1.0000x reference)
//
#include <hip/hip_runtime.h>
#include <stdint.h>
#include <stddef.h>

#define NROWS 8192
#define DIM   1024
#define TEMP  10.0f

typedef __attribute__((ext_vector_type(8))) short bf16x8;
typedef __attribute__((ext_vector_type(4))) float floatx4;

// round-to-nearest-even fp32 -> bf16 bits (inputs are finite, no NaN handling)
__device__ __forceinline__ unsigned short f2bf(float f) {
    unsigned int u = __float_as_uint(f);
    u += 0x7fffu + ((u >> 16) & 1u);
    return (unsigned short)(u >> 16);
}

// async 16B global->LDS (global_load_lds_dwordx4); LDS dest must be
// wave-uniform base + lane*16 -- our staging layout satisfies this.
__device__ __forceinline__ void load16_lds(const unsigned short* g, short* l) {
    __builtin_amdgcn_global_load_lds(
        (__attribute__((address_space(1))) void*)(g),
        (__attribute__((address_space(3))) void*)(l),
        16, 0, 0);
}

// One block per row: L2-normalize a 1024-float row and store as bf16 bits.
// rows [0,8192) -> img, rows [8192,16384) -> txt.
__global__ __launch_bounds__(256) void normalize_kernel(
    const float* __restrict__ img, const float* __restrict__ txt,
    unsigned short* __restrict__ imgn, unsigned short* __restrict__ txtn)
{
    int row = blockIdx.x;
    const float* src;
    unsigned short* dst;
    if (row < NROWS) {
        src = img + (size_t)row * DIM;
        dst = imgn + (size_t)row * DIM;
    } else {
        src = txt + (size_t)(row - NROWS) * DIM;
        dst = txtn + (size_t)(row - NROWS) * DIM;
    }
    int t = threadIdx.x;
    float4 v = ((const float4*)src)[t];   // elements 4t..4t+3
    float ss = v.x * v.x + v.y * v.y + v.z * v.z + v.w * v.w;
#pragma unroll
    for (int off = 32; off > 0; off >>= 1) ss += __shfl_xor(ss, off);
    __shared__ float red[4];
    int wave = t >> 6, lane = t & 63;
    if (lane == 0) red[wave] = ss;
    __syncthreads();
    float tot = red[0] + red[1] + red[2] + red[3];
    float scale = 1.0f / fmaxf(sqrtf(tot), 1e-12f);
    ushort4 o;
    o.x = f2bf(v.x * scale);
    o.y = f2bf(v.y * scale);
    o.z = f2bf(v.z * scale);
    o.w = f2bf(v.w * scale);
    ((ushort4*)dst)[t] = o;
}

// 128x128 tile NT-GEMM (both operands row-major over K) with fused
// sigmoid-loss epilogue + reduction. m97 structure: BK=32, 4 waves of
// 64x64 (4x4 MFMA 16x16x32), global_load_lds width=16, 2-barrier K-loop.
__global__ __launch_bounds__(256) void simloss_kernel(
    const unsigned short* __restrict__ An,   // img normalized bf16 [8192][1024]
    const unsigned short* __restrict__ Bn,   // txt normalized bf16 [8192][1024]
    const float* __restrict__ bias,
    float* __restrict__ out)
{
    __shared__ short As[128 * 32];   // 8 KB, row-major [row][k], stride 32
    __shared__ short Bs[128 * 32];

    const int t = threadIdx.x;
    const int lane = t & 63;
    const int wave = t >> 6;
    const int blockM = blockIdx.x, blockN = blockIdx.y;

    // staging: thread t loads 8 bf16 (16 B); chunk c covers rows c*64..c*64+63
    const int srow = t >> 2;          // 0..63
    const int scol = (t & 3) * 8;     // 0,8,16,24
    const unsigned short* gA0 = An + (size_t)(blockM * 128 + srow) * DIM + scol;
    const unsigned short* gA1 = gA0 + (size_t)64 * DIM;
    const unsigned short* gB0 = Bn + (size_t)(blockN * 128 + srow) * DIM + scol;
    const unsigned short* gB1 = gB0 + (size_t)64 * DIM;
    short* lA0 = &As[t * 8];          // == row*32 + col for chunk 0
    short* lA1 = &As[2048 + t * 8];
    short* lB0 = &Bs[t * 8];
    short* lB1 = &Bs[2048 + t * 8];

    // wave tile: 2x2 waves, each 64x64 output
    const int waveM = (wave >> 1) * 64;
    const int waveN = (wave & 1) * 64;
    const int fr = lane & 15;   // row within 16x16 fragment
    const int fq = lane >> 4;   // quad 0..3 -> k-offset fq*8, C-rows fq*4..+3

    floatx4 acc[4][4];
#pragma unroll
    for (int mi = 0; mi < 4; mi++)
#pragma unroll
        for (int ni = 0; ni < 4; ni++)
            acc[mi][ni] = (floatx4){0.f, 0.f, 0.f, 0.f};

    for (int k0 = 0; k0 < DIM; k0 += 32) {
        __syncthreads();   // previous iter's LDS reads done
        load16_lds(gA0 + k0, lA0);
        load16_lds(gA1 + k0, lA1);
        load16_lds(gB0 + k0, lB0);
        load16_lds(gB1 + k0, lB1);
        asm volatile("s_waitcnt vmcnt(0)" ::: "memory");
        __syncthreads();   // staged tile visible

        bf16x8 a[4], b[4];
#pragma unroll
        for (int mi = 0; mi < 4; mi++)
            a[mi] = *(const bf16x8*)&As[(waveM + mi * 16 + fr) * 32 + fq * 8];
#pragma unroll
        for (int ni = 0; ni < 4; ni++)
            b[ni] = *(const bf16x8*)&Bs[(waveN + ni * 16 + fr) * 32 + fq * 8];
#pragma unroll
        for (int mi = 0; mi < 4; mi++)
#pragma unroll
            for (int ni = 0; ni < 4; ni++)
                acc[mi][ni] = __builtin_amdgcn_mfma_f32_16x16x32_bf16(
                    a[mi], b[ni], acc[mi][ni], 0, 0, 0);
    }

    // fused epilogue: logits = -10*sim + bias; label = +1 diag else -1;
    // loss contribution = softplus(label*logit). C/D map: col=lane&15,
    // row=fq*4+r (final scalar is transpose-invariant, so swap-safe).
    const float biasv = bias[0];
    float local = 0.f;
    const int gi0 = blockM * 128 + waveM + fq * 4;
    const int gj0 = blockN * 128 + waveN + fr;
#pragma unroll
    for (int mi = 0; mi < 4; mi++) {
#pragma unroll
        for (int ni = 0; ni < 4; ni++) {
            const int jg = gj0 + ni * 16;
#pragma unroll
            for (int r = 0; r < 4; r++) {
                float sim = acc[mi][ni][r];
                float logit = fmaf(sim, -TEMP, biasv);
                int ig = gi0 + mi * 16 + r;
                float x = (ig == jg) ? logit : -logit;
                // softplus(x) = max(x,0) + log(1+exp(-|x|)), fast hw transcendentals
                local += fmaxf(x, 0.f) + __logf(1.0f + __expf(-fabsf(x)));
            }
        }
    }
#pragma unroll
    for (int off = 32; off > 0; off >>= 1) local += __shfl_xor(local, off);
    __shared__ float red[4];
    if (lane == 0) red[wave] = local;
    __syncthreads();
    if (t == 0) {
        float tot = (red[0] + red[1] + red[2] + red[3]) * (1.0f / 8192.0f);
        atomicAdd(out, tot);
    }
}

extern "C" void kernel_launch(void* const* d_in, const int* in_sizes, int n_in,
                              void* d_out, int out_size, void* d_ws, size_t ws_size,
                              hipStream_t stream) {
    const float* txt = (const float*)d_in[0];   // text_embeddings [8192][1024]
    const float* img = (const float*)d_in[1];   // image_embeddings [8192][1024]
    const float* bias = (const float*)d_in[2];  // [1]
    float* out = (float*)d_out;

    unsigned short* imgn = (unsigned short*)d_ws;                    // 16 MB
    unsigned short* txtn = imgn + (size_t)NROWS * DIM;               // 16 MB

    // d_out is re-poisoned before every replay; zero it (atomic accumulate target)
    hipMemsetAsync(d_out, 0, sizeof(float), stream);

    normalize_kernel<<<dim3(2 * NROWS), dim3(256), 0, stream>>>(img, txt, imgn, txtn);

    simloss_kernel<<<dim3(NROWS / 128, NROWS / 128), dim3(256), 0, stream>>>(
        imgn, txtn, bias, out);
}

// Round 2
// 201.364 us; speedup vs baseline: 1.3421x; 1.3421x over previous
//
#include <hip/hip_runtime.h>
#include <stdint.h>
#include <stddef.h>

#define NROWS 8192
#define DIM   1024
#define TEMP  10.0f

typedef __attribute__((ext_vector_type(8))) int i32x8;
typedef __attribute__((ext_vector_type(4))) float floatx4;

// async 16B global->LDS (global_load_lds_dwordx4); LDS dest is wave-uniform
// base + lane*16 -- our staging layout is lane-contiguous by construction.
__device__ __forceinline__ void load16_lds(const unsigned char* g, unsigned char* l) {
    __builtin_amdgcn_global_load_lds(
        (__attribute__((address_space(1))) void*)(g),
        (__attribute__((address_space(3))) void*)(l),
        16, 0, 0);
}

// Wave-per-row L2 normalize + fp32 -> fp8 e4m3 (OCP) quantize.
// rows [0,8192) -> img, rows [8192,16384) -> txt. No LDS, no barriers.
__global__ __launch_bounds__(256) void normalize_kernel(
    const float* __restrict__ img, const float* __restrict__ txt,
    unsigned char* __restrict__ imgq, unsigned char* __restrict__ txtq,
    float* __restrict__ out)
{
    const int gw = blockIdx.x * 4 + (threadIdx.x >> 6);   // row id, 0..16383
    const int lane = threadIdx.x & 63;
    const float* src;
    unsigned char* dst;
    if (gw < NROWS) {
        src = img + (size_t)gw * DIM;
        dst = imgq + (size_t)gw * DIM;
    } else {
        src = txt + (size_t)(gw - NROWS) * DIM;
        dst = txtq + (size_t)(gw - NROWS) * DIM;
    }
    float4 v[4];
    float ss = 0.f;
#pragma unroll
    for (int c = 0; c < 4; c++) {
        v[c] = ((const float4*)src)[lane + 64 * c];
        ss += v[c].x * v[c].x + v[c].y * v[c].y + v[c].z * v[c].z + v[c].w * v[c].w;
    }
#pragma unroll
    for (int off = 32; off; off >>= 1) ss += __shfl_xor(ss, off);
    const float scale = 1.0f / fmaxf(sqrtf(ss), 1e-12f);
#pragma unroll
    for (int c = 0; c < 4; c++) {
        int p = 0;
        p = __builtin_amdgcn_cvt_pk_fp8_f32(v[c].x * scale, v[c].y * scale, p, false);
        p = __builtin_amdgcn_cvt_pk_fp8_f32(v[c].z * scale, v[c].w * scale, p, true);
        ((int*)dst)[lane + 64 * c] = p;
    }
    if (gw == 0 && lane == 0) out[0] = 0.f;   // zero the atomic target (replaces memset)
}

// 128x128 tile NT-GEMM on fp8 e4m3 via MX-scaled MFMA 16x16x128 (unit scales),
// BK=128 -> 8 K-iterations. 4 waves x (64x64 = 4x4 fragments). LDS k-chunks
// XOR-swizzled (slot = chunk ^ (((row>>1)&3)<<1)) so fragment reads are
// bank-conflict-free while staging stays lane-contiguous for global_load_lds.
// Fused sigmoid-loss epilogue + reduction (sim matrix never materialized).
__global__ __launch_bounds__(256) void simloss_kernel(
    const unsigned char* __restrict__ An,   // img normalized fp8 [8192][1024]
    const unsigned char* __restrict__ Bn,   // txt normalized fp8 [8192][1024]
    const float* __restrict__ bias,
    float* __restrict__ out)
{
    __shared__ unsigned char As[128 * 128];   // 16 KB, [row][k-swizzled], stride 128B
    __shared__ unsigned char Bs[128 * 128];

    const int t = threadIdx.x;
    const int lane = t & 63;
    const int wave = t >> 6;
    const int blockM = blockIdx.x, blockN = blockIdx.y;

    // staging: thread t loads 16B = global chunk g of row srow (call c adds 32 rows)
    const int srow = t >> 3;                             // 0..31
    const int g = (t & 7) ^ (((t >> 4) & 3) << 1);       // swizzle == (((row>>1)&3)<<1)
    const unsigned char* gA = An + (size_t)(blockM * 128 + srow) * DIM + g * 16;
    const unsigned char* gB = Bn + (size_t)(blockN * 128 + srow) * DIM + g * 16;
    unsigned char* lA = &As[t * 16];
    unsigned char* lB = &Bs[t * 16];

    // wave tile: 2x2 waves, each 64x64 output
    const int waveM = (wave >> 1) * 64;
    const int waveN = (wave & 1) * 64;
    const int fr = lane & 15;    // row/col within 16x16 fragment
    const int fq = lane >> 4;    // quad: holds k in [32*fq, 32*fq+32)
    const int swz = (fr >> 1) & 3;

    floatx4 acc[4][4];
#pragma unroll
    for (int mi = 0; mi < 4; mi++)
#pragma unroll
        for (int ni = 0; ni < 4; ni++)
            acc[mi][ni] = (floatx4){0.f, 0.f, 0.f, 0.f};

    for (int k0 = 0; k0 < DIM; k0 += 128) {
        __syncthreads();   // previous iter's LDS reads done
#pragma unroll
        for (int c = 0; c < 4; c++)
            load16_lds(gA + (size_t)c * 32 * DIM + k0, lA + c * 4096);
#pragma unroll
        for (int c = 0; c < 4; c++)
            load16_lds(gB + (size_t)c * 32 * DIM + k0, lB + c * 4096);
        asm volatile("s_waitcnt vmcnt(0)" ::: "memory");
        __syncthreads();   // staged tile visible

        i32x8 a[4], b[4];
#pragma unroll
        for (int mi = 0; mi < 4; mi++)
            a[mi] = *(const i32x8*)&As[(waveM + mi * 16 + fr) * 128 + (fq ^ swz) * 32];
#pragma unroll
        for (int ni = 0; ni < 4; ni++)
            b[ni] = *(const i32x8*)&Bs[(waveN + ni * 16 + fr) * 128 + (fq ^ swz) * 32];
#pragma unroll
        for (int mi = 0; mi < 4; mi++)
#pragma unroll
            for (int ni = 0; ni < 4; ni++)
                acc[mi][ni] = __builtin_amdgcn_mfma_scale_f32_16x16x128_f8f6f4(
                    a[mi], b[ni], acc[mi][ni],
                    0, 0,                 // cbsz=FP8(e4m3), blgp=FP8(e4m3)
                    0, 0x7f7f7f7f,        // opsel_a, scale_a = 2^0
                    0, 0x7f7f7f7f);       // opsel_b, scale_b = 2^0
    }

    // fused epilogue: logit = -10*sim + bias; label = +1 diag else -1;
    // contribution = softplus(label*logit). C/D map (shape-determined):
    // col=lane&15, row=fq*4+r; final scalar is transpose-invariant.
    const float biasv = bias[0];
    float local = 0.f;
    const int gi0 = blockM * 128 + waveM + fq * 4;
    const int gj0 = blockN * 128 + waveN + fr;
#pragma unroll
    for (int mi = 0; mi < 4; mi++) {
#pragma unroll
        for (int ni = 0; ni < 4; ni++) {
            const int jg = gj0 + ni * 16;
#pragma unroll
            for (int r = 0; r < 4; r++) {
                float sim = acc[mi][ni][r];
                float logit = fmaf(sim, -TEMP, biasv);
                int ig = gi0 + mi * 16 + r;
                float x = (ig == jg) ? logit : -logit;
                // softplus(x) = max(x,0) + log(1+exp(-|x|))
                local += fmaxf(x, 0.f) + __logf(1.0f + __expf(-fabsf(x)));
            }
        }
    }
#pragma unroll
    for (int off = 32; off; off >>= 1) local += __shfl_xor(local, off);
    __shared__ float red[4];
    if (lane == 0) red[wave] = local;
    __syncthreads();
    if (t == 0) {
        float tot = (red[0] + red[1] + red[2] + red[3]) * (1.0f / 8192.0f);
        atomicAdd(out, tot);
    }
}

extern "C" void kernel_launch(void* const* d_in, const int* in_sizes, int n_in,
                              void* d_out, int out_size, void* d_ws, size_t ws_size,
                              hipStream_t stream) {
    const float* txt = (const float*)d_in[0];   // text_embeddings [8192][1024]
    const float* img = (const float*)d_in[1];   // image_embeddings [8192][1024]
    const float* bias = (const float*)d_in[2];  // [1]
    float* out = (float*)d_out;

    unsigned char* imgq = (unsigned char*)d_ws;                      // 8 MB fp8
    unsigned char* txtq = imgq + (size_t)NROWS * DIM;                // 8 MB fp8

    normalize_kernel<<<dim3(2 * NROWS / 4), dim3(256), 0, stream>>>(
        img, txt, imgq, txtq, out);

    simloss_kernel<<<dim3(NROWS / 128, NROWS / 128), dim3(256), 0, stream>>>(
        imgq, txtq, bias, out);
}

// Round 3
// 177.229 us; speedup vs baseline: 1.5248x; 1.1362x over previous
//
#include <hip/hip_runtime.h>
#include <stdint.h>
#include <stddef.h>

#define NROWS 8192
#define DIM   1024
#define TEMP  10.0f

#define BM 256
#define BN 128
#define BK 128

typedef __attribute__((ext_vector_type(8))) int i32x8;
typedef __attribute__((ext_vector_type(4))) float floatx4;

// async 16B global->LDS (global_load_lds_dwordx4); LDS dest is wave-uniform
// base + lane*16 -- staging dest is t*16 by construction.
__device__ __forceinline__ void load16_lds(const unsigned char* g, unsigned char* l) {
    __builtin_amdgcn_global_load_lds(
        (__attribute__((address_space(1))) void*)(g),
        (__attribute__((address_space(3))) void*)(l),
        16, 0, 0);
}

// Wave-per-row L2 normalize + fp32 -> fp8 e4m3 (OCP) quantize.
// rows [0,8192) -> img, rows [8192,16384) -> txt. No LDS, no barriers.
__global__ __launch_bounds__(256) void normalize_kernel(
    const float* __restrict__ img, const float* __restrict__ txt,
    unsigned char* __restrict__ imgq, unsigned char* __restrict__ txtq,
    float* __restrict__ out)
{
    const int gw = blockIdx.x * 4 + (threadIdx.x >> 6);   // row id, 0..16383
    const int lane = threadIdx.x & 63;
    const float* src;
    unsigned char* dst;
    if (gw < NROWS) {
        src = img + (size_t)gw * DIM;
        dst = imgq + (size_t)gw * DIM;
    } else {
        src = txt + (size_t)(gw - NROWS) * DIM;
        dst = txtq + (size_t)(gw - NROWS) * DIM;
    }
    float4 v[4];
    float ss = 0.f;
#pragma unroll
    for (int c = 0; c < 4; c++) {
        v[c] = ((const float4*)src)[lane + 64 * c];
        ss += v[c].x * v[c].x + v[c].y * v[c].y + v[c].z * v[c].z + v[c].w * v[c].w;
    }
#pragma unroll
    for (int off = 32; off; off >>= 1) ss += __shfl_xor(ss, off);
    const float scale = 1.0f / fmaxf(sqrtf(ss), 1e-12f);
#pragma unroll
    for (int c = 0; c < 4; c++) {
        int p = 0;
        p = __builtin_amdgcn_cvt_pk_fp8_f32(v[c].x * scale, v[c].y * scale, p, false);
        p = __builtin_amdgcn_cvt_pk_fp8_f32(v[c].z * scale, v[c].w * scale, p, true);
        ((int*)dst)[lane + 64 * c] = p;
    }
    if (gw == 0 && lane == 0) out[0] = 0.f;   // zero the atomic target
}

// Load one 32B A/B fragment (k in [32fq,32fq+32) of `row`) from the
// 16B-swizzled LDS tile: slot(k16) = k16 ^ (row&7). o0 = slot(2fq)*16
// precomputed per lane; second half lives at o0^16. Bank math: per b128,
// each 16B slot serves exactly 2 lanes (2-way = free), all 32 banks used.
__device__ __forceinline__ i32x8 ldfrag(const unsigned char* base, int row, int o0) {
    const int4 lo = *(const int4*)(base + row * BK + o0);
    const int4 hi = *(const int4*)(base + row * BK + (o0 ^ 16));
    i32x8 r;
    r[0] = lo.x; r[1] = lo.y; r[2] = lo.z; r[3] = lo.w;
    r[4] = hi.x; r[5] = hi.y; r[6] = hi.z; r[7] = hi.w;
    return r;
}

// 256x128 tile NT-GEMM on fp8 e4m3 via MX-scaled MFMA 16x16x128 (unit
// scales), BK=128 -> 8 K-iterations. 4 waves (2x2), wave tile 128x64
// (8x4 fragments, acc=128 VGPR). LDS 16B-chunk XOR swizzle -> conflict-free
// fragment reads while staging stays lane-contiguous for global_load_lds.
// Fused sigmoid-loss epilogue + reduction (sim matrix never materialized).
__global__ __launch_bounds__(256, 2) void simloss_kernel(
    const unsigned char* __restrict__ An,   // img normalized fp8 [8192][1024]
    const unsigned char* __restrict__ Bn,   // txt normalized fp8 [8192][1024]
    const float* __restrict__ bias,
    float* __restrict__ out)
{
    __shared__ unsigned char As[BM * BK];   // 32 KB, [row][k16-swizzled]
    __shared__ unsigned char Bs[BN * BK];   // 16 KB

    const int t = threadIdx.x;
    const int lane = t & 63;
    const int wave = t >> 6;
    const int blockM = blockIdx.x, blockN = blockIdx.y;

    // staging: thread t -> LDS row (t>>3)+32c, slot t&7; source chunk
    // g = slot ^ (row&7)  (16B-granular XOR swizzle)
    const int srow = t >> 3;                       // 0..31
    const int g = (t & 7) ^ ((t >> 3) & 7);
    const unsigned char* gA = An + (size_t)(blockM * BM + srow) * DIM + g * 16;
    const unsigned char* gB = Bn + (size_t)(blockN * BN + srow) * DIM + g * 16;
    unsigned char* lA = &As[t * 16];
    unsigned char* lB = &Bs[t * 16];

    // wave tile: 2x2 waves, each 128x64 output (mi 0..7, ni 0..3)
    const int waveM = (wave >> 1) * 128;
    const int waveN = (wave & 1) * 64;
    const int fr = lane & 15;    // row/col within 16x16 fragment
    const int fq = lane >> 4;    // quad: holds k in [32fq, 32fq+32)
    const int o0 = ((2 * fq) ^ (fr & 7)) * 16;

    floatx4 acc[8][4];
#pragma unroll
    for (int mi = 0; mi < 8; mi++)
#pragma unroll
        for (int ni = 0; ni < 4; ni++)
            acc[mi][ni] = (floatx4){0.f, 0.f, 0.f, 0.f};

    for (int k0 = 0; k0 < DIM; k0 += BK) {
        __syncthreads();   // previous iter's LDS reads done
#pragma unroll
        for (int c = 0; c < 8; c++)
            load16_lds(gA + (size_t)c * 32 * DIM + k0, lA + c * 4096);
#pragma unroll
        for (int c = 0; c < 4; c++)
            load16_lds(gB + (size_t)c * 32 * DIM + k0, lB + c * 4096);
        asm volatile("s_waitcnt vmcnt(0)" ::: "memory");
        __syncthreads();   // staged tile visible

        i32x8 b[4];
#pragma unroll
        for (int ni = 0; ni < 4; ni++)
            b[ni] = ldfrag(Bs, waveN + ni * 16 + fr, o0);
#pragma unroll
        for (int mi = 0; mi < 8; mi++) {
            i32x8 a = ldfrag(As, waveM + mi * 16 + fr, o0);
#pragma unroll
            for (int ni = 0; ni < 4; ni++)
                acc[mi][ni] = __builtin_amdgcn_mfma_scale_f32_16x16x128_f8f6f4(
                    a, b[ni], acc[mi][ni],
                    0, 0,                 // cbsz=FP8(e4m3), blgp=FP8(e4m3)
                    0, 0x7f7f7f7f,        // opsel_a, scale_a = 2^0
                    0, 0x7f7f7f7f);       // opsel_b, scale_b = 2^0
        }
    }

    // fused epilogue: logit = -10*sim + bias; label = +1 diag else -1;
    // contribution = softplus(label*logit). C/D map (shape-determined):
    // col=lane&15, row=fq*4+r; final scalar is transpose-invariant.
    const float biasv = bias[0];
    float local = 0.f;
    const int gi0 = blockM * BM + waveM + fq * 4;
    const int gj0 = blockN * BN + waveN + fr;
#pragma unroll
    for (int mi = 0; mi < 8; mi++) {
#pragma unroll
        for (int ni = 0; ni < 4; ni++) {
            const int jg = gj0 + ni * 16;
#pragma unroll
            for (int r = 0; r < 4; r++) {
                float sim = acc[mi][ni][r];
                float logit = fmaf(sim, -TEMP, biasv);
                int ig = gi0 + mi * 16 + r;
                float x = (ig == jg) ? logit : -logit;
                // softplus(x) = max(x,0) + log(1+exp(-|x|))
                local += fmaxf(x, 0.f) + __logf(1.0f + __expf(-fabsf(x)));
            }
        }
    }
#pragma unroll
    for (int off = 32; off; off >>= 1) local += __shfl_xor(local, off);
    __shared__ float red[4];
    if (lane == 0) red[wave] = local;
    __syncthreads();
    if (t == 0) {
        float tot = (red[0] + red[1] + red[2] + red[3]) * (1.0f / 8192.0f);
        atomicAdd(out, tot);
    }
}

extern "C" void kernel_launch(void* const* d_in, const int* in_sizes, int n_in,
                              void* d_out, int out_size, void* d_ws, size_t ws_size,
                              hipStream_t stream) {
    const float* txt = (const float*)d_in[0];   // text_embeddings [8192][1024]
    const float* img = (const float*)d_in[1];   // image_embeddings [8192][1024]
    const float* bias = (const float*)d_in[2];  // [1]
    float* out = (float*)d_out;

    unsigned char* imgq = (unsigned char*)d_ws;                      // 8 MB fp8
    unsigned char* txtq = imgq + (size_t)NROWS * DIM;                // 8 MB fp8

    normalize_kernel<<<dim3(2 * NROWS / 4), dim3(256), 0, stream>>>(
        img, txt, imgq, txtq, out);

    simloss_kernel<<<dim3(NROWS / BM, NROWS / BN), dim3(256), 0, stream>>>(
        imgq, txtq, bias, out);
}